// Round 6
// baseline (357.104 us; speedup 1.0000x reference)
//
#include <hip/hip_runtime.h>
#include <math.h>

// ---------------- problem constants ----------------
#define NPIX 128
#define MASKM 2548
#define NPAD 2560          // padded q count (20*128)
#define MG   6912          // GEMM M = 9 taps * 768
#define KD   768

typedef __attribute__((ext_vector_type(8))) short bf16x8;
typedef __attribute__((ext_vector_type(4))) float f32x4;
typedef __attribute__((ext_vector_type(16))) float f32x16;
typedef __attribute__((ext_vector_type(8))) unsigned short ushort8;

// ---------------- workspace layout ----------------
static constexpr size_t OFF_QI   = 0;
static constexpr size_t OFF_QJ   = OFF_QI + NPAD * 4;
static constexpr size_t OFF_QIDX = OFF_QJ + NPAD * 4;
static constexpr size_t OFF_APIX = OFF_QIDX + 16384 * 4;
static constexpr size_t OFF_START= OFF_APIX + 16384 * 4;
static constexpr size_t OFF_PART = OFF_START + 128 * 4;
static constexpr size_t OFF_STAT = OFF_PART + 512 * 8 * 8;
static constexpr size_t OFF_SC   = OFF_STAT + 256;
static constexpr size_t OFF_HM   = OFF_SC + NPAD * 4;
static constexpr size_t OFF_AH   = OFF_HM + (size_t)MASKM * KD * 4;
static constexpr size_t OFF_AL   = OFF_AH + (size_t)MG * KD * 2;
static constexpr size_t OFF_BH   = OFF_AL + (size_t)MG * KD * 2;
static constexpr size_t OFF_BL   = OFF_BH + (size_t)NPAD * KD * 2;
static constexpr size_t OFF_YT   = OFF_BL + (size_t)NPAD * KD * 2;
// X (7.9MB fp32) aliases the head of Yt (70.8MB): dead before k_gemm writes Yt.
static constexpr size_t OFF_X    = OFF_YT;

// ---------------- bf16 hi/lo split helpers ----------------
__device__ __forceinline__ unsigned short f2bf(float f) {
    unsigned u = __float_as_uint(f);
    u = u + 0x7FFFu + ((u >> 16) & 1u);       // RNE
    return (unsigned short)(u >> 16);
}
__device__ __forceinline__ float bf2f(unsigned short h) {
    return __uint_as_float(((unsigned)h) << 16);
}

// ---------------- mask structure (closed form) ----------------
__device__ __forceinline__ bool mask_allowed(int i, int d) {
    if (d == 0) return true;
    if (d <= 15) return true;
    if (d <= 31) return (d >= 17) && ((d & 1) == 1) && ((i & 1) == 0);
    if (d <= 63) return (d >= 35) && ((d & 3) == 3) && ((i & 3) == 0);
    return (d >= 71) && ((d & 7) == 7) && ((i & 7) == 0);
}
__device__ __forceinline__ bool masked_ij(int i, int j) {
    return (j >= i) && (j < NPIX) && (i >= 0) && mask_allowed(i, j - i);
}

// 64 blocks x 256: one thread per pixel -> qidx, apix, qi/qj.
// Row-start offsets recomputed per block in LDS (absorbs old k_rowstart).
// Block 0 also zeroes the 8 GN accumulator doubles (read by k_score).
__global__ void k_fill(int* __restrict__ qi, int* __restrict__ qj,
                       int* __restrict__ qidx, int* __restrict__ apix,
                       double* __restrict__ part) {
    __shared__ int cnt[NPIX];
    __shared__ int startv[NPIX];
    int tid = threadIdx.x;
    if (tid < NPIX) {
        int c = 0;
        for (int d = 0; tid + d < NPIX; ++d) if (mask_allowed(tid, d)) ++c;
        cnt[tid] = c;
    }
    __syncthreads();
    if (tid == 0) {
        int s = 0;
        for (int r = 0; r < NPIX; ++r) { startv[r] = s; s += cnt[r]; }
    }
    __syncthreads();
    int p = blockIdx.x * 256 + tid;
    int i = p >> 7, j = p & 127;
    int q = -1;
    if (masked_ij(i, j)) {
        int d = j - i, r = 0;
        for (int dd = 0; dd < d; ++dd) r += mask_allowed(i, dd) ? 1 : 0;
        q = startv[i] + r;
        qi[q] = i; qj[q] = j;
    }
    qidx[p] = q;
    int act = 0;
    #pragma unroll
    for (int dy = -1; dy <= 1; ++dy)
        #pragma unroll
        for (int dx = -1; dx <= 1; ++dx)
            if (masked_ij(i + dy, j + dx)) act = 1;
    apix[p] = act;
    if (blockIdx.x == 0 && tid < 8) part[tid] = 0.0;
}

// ---------------- X[c][q] = max(fea[c, i..j]) via sparse table ----------------
__global__ void k_buildX(const float* __restrict__ fea, const int* __restrict__ qi,
                         const int* __restrict__ qj, float* __restrict__ X) {
    __shared__ float tab[8][NPIX];
    int c = blockIdx.x, t = threadIdx.x;    // 128 threads
    tab[0][t] = fea[c * NPIX + t];
    __syncthreads();
    #pragma unroll
    for (int l = 1; l < 8; ++l) {
        int half = 1 << (l - 1), full = 1 << l;
        if (t + full <= NPIX) tab[l][t] = fmaxf(tab[l - 1][t], tab[l - 1][t + half]);
        __syncthreads();
    }
    #pragma unroll
    for (int it = 0; it < 20; ++it) {
        int q = it * 128 + t;
        float v = 0.f;
        if (q < MASKM) {
            int i = qi[q], j = qj[q];
            int len = j - i + 1;
            int l = 31 - __clz(len);
            v = fmaxf(tab[l][i], tab[l][j + 1 - (1 << l)]);
        }
        X[c * NPAD + q] = v;
    }
}

// ---------------- fused reorder+split: w1[co][ci*9+tap] -> Ah/Al[(tap*768+co)][ci] ----------------
#define PASTR 148   // padded float stride (148*4 B: 16B-aligned, non-pow2 banks)
__global__ __launch_bounds__(256) void k_prepA(const float* __restrict__ w1,
                                               unsigned short* __restrict__ Ah,
                                               unsigned short* __restrict__ Al) {
    __shared__ float tile[64 * PASTR];   // [co 64][ci16*9tap = 144 used]
    int co0 = blockIdx.x * 64, ci0 = blockIdx.y * 64;
    int tid = threadIdx.x;
    for (int s = 0; s < 4; ++s) {
        int cib = ci0 + s * 16;
        __syncthreads();
        for (int idx = tid; idx < 2304; idx += 256) {
            int row = idx / 36, c4 = idx % 36;
            float4 v = *(const float4*)(w1 + (size_t)(co0 + row) * MG + cib * 9 + c4 * 4);
            *(float4*)&tile[row * PASTR + c4 * 4] = v;
        }
        __syncthreads();
        for (int idx = tid; idx < 1152; idx += 256) {
            int tap = idx / 128;
            int rem = idx - tap * 128;
            int co = rem >> 1, half = rem & 1;
            ushort8 vh, vl;
            #pragma unroll
            for (int c = 0; c < 8; ++c) {
                float v = tile[co * PASTR + (half * 8 + c) * 9 + tap];
                unsigned short hi = f2bf(v);
                vh[c] = hi;
                vl[c] = f2bf(v - bf2f(hi));
            }
            size_t ob = (size_t)(tap * 768 + co0 + co) * KD + cib + half * 8;
            *(ushort8*)(Ah + ob) = vh;
            *(ushort8*)(Al + ob) = vl;
        }
    }
}

// ---------------- transpose + bf16 hi/lo split: src[768][C] -> dst[C][768] ----------------
__global__ void k_trans(const float* __restrict__ src, int C,
                        unsigned short* __restrict__ dh, unsigned short* __restrict__ dl) {
    __shared__ float tile[64][65];
    int c0 = blockIdx.x * 64, k0 = blockIdx.y * 64;
    int t = threadIdx.x;
    int r = t >> 2, cq = (t & 3) << 4;
    const float* s = src + (size_t)(k0 + r) * C + c0 + cq;
    #pragma unroll
    for (int u = 0; u < 16; u += 4) {
        float4 v = *(const float4*)(s + u);
        tile[r][cq + u]     = v.x;
        tile[r][cq + u + 1] = v.y;
        tile[r][cq + u + 2] = v.z;
        tile[r][cq + u + 3] = v.w;
    }
    __syncthreads();
    size_t ob = (size_t)(c0 + r) * KD + k0 + cq;
    #pragma unroll
    for (int u = 0; u < 16; ++u) {
        float v = tile[cq + u][r];
        unsigned short hi = f2bf(v);
        float lo = v - bf2f(hi);
        dh[ob + u] = hi;
        dl[ob + u] = f2bf(lo);
    }
}

// ---------------- bf16x3 MFMA GEMM: Yt[n][m] = sum_k A[m][k] * B[n][k] ----------------
// 32x32x16 MFMA, BM=256 BN=320 BK=32, grid = 216 = 8 XCD x 27 (one round).
// Chunk-major LDS slots (R4: measured 0 bank conflicts).
// R5 post-mortem: __launch_bounds__(512,2) capped arch-VGPR at 128; the deep
// pipeline's 22 live fragments (88 VGPR) + staging + addressing spilled to
// scratch (FETCH +36MB, WRITE +12.5MB, dur 96->170). The cap bought NOTHING:
// 144KB LDS already limits to 1 block/CU = 2 waves/SIMD regardless of regs.
// R6: __launch_bounds__(512,1) -> full 512-reg/wave budget, no spill; same
// program order as R5: [14 ks0 reads][8 ks1 front][30 MFMA][6 ks1 tail][30 MFMA]
// so compiler-counted lgkmcnt hides ks1 reads under the ks0 MFMA cluster.
#define BUFSZ   73728      // Ah(16K) | Al(16K) | Bh(20K) | Bl(20K)
#define SB_BH   32768

__global__ __launch_bounds__(512, 1) void k_gemm(const unsigned short* __restrict__ Ah,
                                                 const unsigned short* __restrict__ Al,
                                                 const unsigned short* __restrict__ Bh,
                                                 const unsigned short* __restrict__ Bl,
                                                 float* __restrict__ Yt) {
    extern __shared__ char sm[];               // 2 * BUFSZ = 144 KB dynamic LDS
    int tid = threadIdx.x;
    int wave = tid >> 6, lane = tid & 63;

    int bid = (int)blockIdx.x;
    int xcd = bid & 7, loc = bid >> 3;         // 8 XCDs x 27 M-tiles
    int m0 = loc * 256, n0 = xcd * 320;

    int wm = (wave & 3) << 6, wn = (wave >> 2) * 160;  // 4M x 2N waves, 64x160/wave
    int r32 = lane & 31, hi2 = lane >> 5;
    // common fragment-read base: slot(row>>4)*1024 + hi2*256 + (row&15)*16
    int rb  = (r32 >> 4) * 1024 + hi2 * 256 + (r32 & 15) * 16;
    int awb = (wm >> 4) * 1024 + rb;
    int bwb = (wn >> 4) * 1024 + rb;

    // 9 stage slots per wave: gid = wave*9+s over 72 total.
    // gid 0-15: Ah 16-row slots; 16-31: Al; 32-51: Bh; 52-71: Bl.
    // chunk-major staging: lane stages row (lane&15), k-chunk (lane>>4).
    int lrow = lane & 15, lchk = lane >> 4;
    const unsigned short* sp[9];
    int so[9];
    #pragma unroll
    for (int s = 0; s < 9; ++s) {
        int gid = wave * 9 + s;
        const unsigned short* base;
        int row0, ldso;
        if (gid < 16)      { base = Ah; row0 = m0 + gid * 16;        ldso = gid * 1024; }
        else if (gid < 32) { base = Al; row0 = m0 + (gid - 16) * 16; ldso = 16384 + (gid - 16) * 1024; }
        else if (gid < 52) { base = Bh; row0 = n0 + (gid - 32) * 16; ldso = SB_BH + (gid - 32) * 1024; }
        else               { base = Bl; row0 = n0 + (gid - 52) * 16; ldso = SB_BH + 20480 + (gid - 52) * 1024; }
        sp[s] = base + (size_t)(row0 + lrow) * KD + lchk * 8;
        so[s] = ldso;
    }

    f32x16 acc[2][5] = {};                     // 2 m-frags x 5 n-frags of 32x32

    char* CB = sm;                             // compute buffer
    char* NB = sm + BUFSZ;                     // staging buffer (next tile)

    #define STAGE(DST, s, koff) __builtin_amdgcn_global_load_lds( \
        (const __attribute__((address_space(1))) unsigned int*)(sp[s] + (koff)), \
        (__attribute__((address_space(3))) unsigned int*)((DST) + so[s]), 16, 0, 0)
    #define ARD(hl, mf, ks) (*(const bf16x8*)(CB + (hl) * 16384 + awb + (mf) * 2048 + (ks) * 512))
    #define BRD(hl, nf, ks) (*(const bf16x8*)(CB + SB_BH + (hl) * 20480 + bwb + (nf) * 2048 + (ks) * 512))
    #define TRIP(mf, nf, xh, xl, yh, yl) \
        acc[mf][nf] = __builtin_amdgcn_mfma_f32_32x32x16_bf16(xh, yh, acc[mf][nf], 0, 0, 0); \
        acc[mf][nf] = __builtin_amdgcn_mfma_f32_32x32x16_bf16(xh, yl, acc[mf][nf], 0, 0, 0); \
        acc[mf][nf] = __builtin_amdgcn_mfma_f32_32x32x16_bf16(xl, yh, acc[mf][nf], 0, 0, 0);

    // prologue: stage tile 0 into CB; __syncthreads drains vmcnt.
    #pragma unroll
    for (int s = 0; s < 9; ++s) STAGE(CB, s, 0);
    __syncthreads();

    for (int t = 0; t < 24; ++t) {             // K = 768 = 24 tiles of 32
        int kn = (t + 1) * 32;
        bool stg = (t < 23);
        // ks0 operands (14 reads)
        bf16x8 a0h = ARD(0, 0, 0), a0l = ARD(1, 0, 0);
        bf16x8 a1h = ARD(0, 1, 0), a1l = ARD(1, 1, 0);
        bf16x8 b0h = BRD(0, 0, 0), b0l = BRD(1, 0, 0);
        bf16x8 b1h = BRD(0, 1, 0), b1l = BRD(1, 1, 0);
        bf16x8 b2h = BRD(0, 2, 0), b2l = BRD(1, 2, 0);
        bf16x8 b3h = BRD(0, 3, 0), b3l = BRD(1, 3, 0);
        bf16x8 b4h = BRD(0, 4, 0), b4l = BRD(1, 4, 0);
        // ks1 front operands (8 reads) — in flight across MFMA cluster 0
        bf16x8 c0h = ARD(0, 0, 1), c0l = ARD(1, 0, 1);
        bf16x8 c1h = ARD(0, 1, 1), c1l = ARD(1, 1, 1);
        bf16x8 d0h = BRD(0, 0, 1), d0l = BRD(1, 0, 1);
        bf16x8 d1h = BRD(0, 1, 1), d1l = BRD(1, 1, 1);
        // next-tile staging (VMEM pipe, drains at tile-end barrier)
        if (stg) {
            #pragma unroll
            for (int s = 0; s < 9; ++s) STAGE(NB, s, kn);
        }
        __builtin_amdgcn_s_setprio(1);
        TRIP(0, 0, a0h, a0l, b0h, b0l)
        TRIP(1, 0, a1h, a1l, b0h, b0l)
        TRIP(0, 1, a0h, a0l, b1h, b1l)
        TRIP(1, 1, a1h, a1l, b1h, b1l)
        TRIP(0, 2, a0h, a0l, b2h, b2l)
        TRIP(1, 2, a1h, a1l, b2h, b2l)
        TRIP(0, 3, a0h, a0l, b3h, b3l)
        TRIP(1, 3, a1h, a1l, b3h, b3l)
        TRIP(0, 4, a0h, a0l, b4h, b4l)
        TRIP(1, 4, a1h, a1l, b4h, b4l)
        __builtin_amdgcn_s_setprio(0);
        // ks1 tail operands (6 reads) — hide under MFMA cluster 1 via counted lgkm
        bf16x8 d2h = BRD(0, 2, 1), d2l = BRD(1, 2, 1);
        bf16x8 d3h = BRD(0, 3, 1), d3l = BRD(1, 3, 1);
        bf16x8 d4h = BRD(0, 4, 1), d4l = BRD(1, 4, 1);
        __builtin_amdgcn_s_setprio(1);
        TRIP(0, 0, c0h, c0l, d0h, d0l)
        TRIP(1, 0, c1h, c1l, d0h, d0l)
        TRIP(0, 1, c0h, c0l, d1h, d1l)
        TRIP(1, 1, c1h, c1l, d1h, d1l)
        TRIP(0, 2, c0h, c0l, d2h, d2l)
        TRIP(1, 2, c1h, c1l, d2h, d2l)
        TRIP(0, 3, c0h, c0l, d3h, d3l)
        TRIP(1, 3, c1h, c1l, d3h, d3l)
        TRIP(0, 4, c0h, c0l, d4h, d4l)
        TRIP(1, 4, c1h, c1l, d4h, d4l)
        __builtin_amdgcn_s_setprio(0);

        // tile boundary: drains vmcnt (next-tile stages resident) and gates the
        // buffer swap (all waves done reading CB).
        __syncthreads();
        char* tmp = CB; CB = NB; NB = tmp;
    }

    // epilogue: C/D layout of 32x32: col(n)=lane&31, row(m)=(reg&3)+8*(reg>>2)+4*(lane>>5)
    #pragma unroll
    for (int mf = 0; mf < 2; ++mf)
        #pragma unroll
        for (int nf = 0; nf < 5; ++nf) {
            int n = n0 + wn + nf * 32 + r32;
            size_t rowb = (size_t)n * MG + m0 + wm + mf * 32 + 4 * hi2;
            #pragma unroll
            for (int g = 0; g < 4; ++g) {
                f32x4 v = { acc[mf][nf][g * 4 + 0], acc[mf][nf][g * 4 + 1],
                            acc[mf][nf][g * 4 + 2], acc[mf][nf][g * 4 + 3] };
                *(f32x4*)(Yt + rowb + 8 * g) = v;
            }
        }
    #undef STAGE
    #undef ARD
    #undef BRD
    #undef TRIP
}

// ---------------- gather taps -> hm (masked rows) + GN partial sums (active pixels only) ----------------
__global__ __launch_bounds__(256) void k_gather(const float* __restrict__ Yt,
                                                const int* __restrict__ qidx,
                                                const int* __restrict__ apix,
                                                float* __restrict__ hm,
                                                double* __restrict__ part) {
    __shared__ double red1[256 * 4], red2[256 * 4];
    int tid = threadIdx.x;
    int wave = tid >> 6, lane = tid & 63;
    double a1[3] = {0, 0, 0}, a2[3] = {0, 0, 0};
    int gs[3];
    #pragma unroll
    for (int s = 0; s < 3; ++s) gs[s] = (64 * s + lane) / 48;

    for (int it = 0; it < 8; ++it) {
        int p = blockIdx.x * 32 + wave * 8 + it;   // wave-uniform pixel
        if (!apix[p]) continue;
        int y = p >> 7, x = p & 127;
        float4 hv[3] = {};
        #pragma unroll
        for (int tap = 0; tap < 9; ++tap) {
            int i = y + tap / 3 - 1, j = x + tap % 3 - 1;
            if ((unsigned)i < 128u && (unsigned)j < 128u) {
                int q = qidx[i * NPIX + j];
                if (q >= 0) {
                    const float* yr = Yt + (size_t)q * MG + tap * 768 + lane * 4;
                    #pragma unroll
                    for (int s = 0; s < 3; ++s) {
                        float4 v = *(const float4*)(yr + s * 256);
                        hv[s].x += v.x; hv[s].y += v.y; hv[s].z += v.z; hv[s].w += v.w;
                    }
                }
            }
        }
        int qp = qidx[p];
        if (qp >= 0) {
            #pragma unroll
            for (int s = 0; s < 3; ++s)
                *(float4*)(hm + (size_t)qp * KD + s * 256 + lane * 4) = hv[s];
        }
        #pragma unroll
        for (int s = 0; s < 3; ++s) {
            a1[s] += (double)hv[s].x + (double)hv[s].y + (double)hv[s].z + (double)hv[s].w;
            a2[s] += (double)hv[s].x * hv[s].x + (double)hv[s].y * hv[s].y +
                     (double)hv[s].z * hv[s].z + (double)hv[s].w * hv[s].w;
        }
    }
    #pragma unroll
    for (int g = 0; g < 4; ++g) { red1[tid * 4 + g] = 0.0; red2[tid * 4 + g] = 0.0; }
    #pragma unroll
    for (int s = 0; s < 3; ++s) { red1[tid * 4 + gs[s]] = a1[s]; red2[tid * 4 + gs[s]] = a2[s]; }
    __syncthreads();
    if (tid < 8) {
        int g = tid & 3;
        double s = 0.0;
        if (tid < 4) { for (int i = 0; i < 256; ++i) s += red1[i * 4 + g]; }
        else         { for (int i = 0; i < 256; ++i) s += red2[i * 4 + g]; }
        atomicAdd(&part[tid], s);
    }
}

// ---------------- fused GN + ReLU + 1x1 conv + sigmoid at mask positions ----------------
__global__ void k_score(const float* __restrict__ hm, const double* __restrict__ part,
                        const float* __restrict__ gamma, const float* __restrict__ beta,
                        const float* __restrict__ w2, const float* __restrict__ b2,
                        float* __restrict__ scores) {
    int q = blockIdx.x * 4 + (threadIdx.x >> 6);
    int lane = threadIdx.x & 63;
    if (q >= MASKM) return;
    float mu[4], rs[4];
    const double cnt = 192.0 * 16384.0;
    #pragma unroll
    for (int g = 0; g < 4; ++g) {
        double m = part[g] / cnt;
        double v = part[4 + g] / cnt - m * m;
        mu[g] = (float)m;
        rs[g] = (float)(1.0 / sqrt(v + 1e-5));
    }
    const float* hp = hm + (size_t)q * KD;
    float s = 0.f;
    for (int c = lane; c < KD; c += 64) {
        int g = c / 192;
        float v = (hp[c] - mu[g]) * rs[g] * gamma[c] + beta[c];
        s += fmaxf(v, 0.f) * w2[c];
    }
    for (int o = 32; o; o >>= 1) s += __shfl_down(s, o, 64);
    if (lane == 0) scores[q] = 1.f / (1.f + expf(-(s + b2[0])));
}

// ---------------- greedy NMS via 5-round iterative argmax (== stable sorted greedy) ----------------
__device__ __forceinline__ unsigned long long shfl_down_u64(unsigned long long v, int o) {
    unsigned lo = (unsigned)v, hi = (unsigned)(v >> 32);
    lo = __shfl_down(lo, o, 64);
    hi = __shfl_down(hi, o, 64);
    return ((unsigned long long)hi << 32) | lo;
}

__global__ void k_nms(const float* __restrict__ scores, const int* __restrict__ qi,
                      const int* __restrict__ qj, const int* __restrict__ durp,
                      float* __restrict__ out) {
    __shared__ unsigned long long key[MASKM];
    __shared__ float ss[MASKM], ee[MASKM];
    __shared__ unsigned char st[MASKM];     // 0 free, 1 suppressed, 2 kept, 3 picked-fallback
    __shared__ unsigned long long wm0[16], wm1[16];
    __shared__ int sh_keeper, keepq[5];
    __shared__ float sh_s0, sh_e0;
    int t = threadIdx.x;                    // 1024
    float delta = (float)(*durp) / 128.f;
    for (int i = t; i < MASKM; i += 1024) {
        unsigned sb = __float_as_uint(scores[i]);            // scores > 0: bits monotonic
        key[i] = ((unsigned long long)sb << 32) | (unsigned)(4095 - i);  // tie: lower q wins
        ss[i] = qi[i] * delta;
        ee[i] = (qj[i] + 1) * delta;
        st[i] = 0;
    }
    __syncthreads();
    for (int round = 0; round < 5; ++round) {
        unsigned long long b0 = 0, b1 = 0;
        for (int i = t; i < MASKM; i += 1024) {
            unsigned char s = st[i];
            unsigned long long k = key[i];
            if (s == 0) { if (k > b0) b0 = k; }
            else if (s == 1) { if (k > b1) b1 = k; }
        }
        for (int o = 32; o; o >>= 1) {
            unsigned long long u0 = shfl_down_u64(b0, o), u1 = shfl_down_u64(b1, o);
            if (u0 > b0) b0 = u0;
            if (u1 > b1) b1 = u1;
        }
        if ((t & 63) == 0) { wm0[t >> 6] = b0; wm1[t >> 6] = b1; }
        __syncthreads();
        if (t == 0) {
            unsigned long long B0 = 0, B1 = 0;
            for (int w = 0; w < 16; ++w) {
                if (wm0[w] > B0) B0 = wm0[w];
                if (wm1[w] > B1) B1 = wm1[w];
            }
            int keeper = (B0 != 0);
            unsigned long long B = keeper ? B0 : B1;
            int q = 4095 - (int)(B & 0xFFFFFFFFull);
            st[q] = keeper ? 2 : 3;
            sh_keeper = keeper;
            sh_s0 = ss[q]; sh_e0 = ee[q];
            keepq[round] = q;
        }
        __syncthreads();
        if (sh_keeper) {
            float s0 = sh_s0, e0 = sh_e0;
            for (int i = t; i < MASKM; i += 1024) {
                if (st[i] == 0) {
                    float inter = fminf(ee[i], e0) - fmaxf(ss[i], s0);
                    if (inter > 0.f) {
                        float uni = fmaxf(ee[i], e0) - fminf(ss[i], s0);
                        if (inter / uni > 0.5f) st[i] = 1;
                    }
                }
            }
        }
        __syncthreads();
    }
    if (t < 5) { out[t * 2] = ss[keepq[t]]; out[t * 2 + 1] = ee[keepq[t]]; }
}

// ---------------- launch ----------------
extern "C" void kernel_launch(void* const* d_in, const int* in_sizes, int n_in,
                              void* d_out, int out_size, void* d_ws, size_t ws_size,
                              hipStream_t stream) {
    const float* fea   = (const float*)d_in[0];
    const int*   dur   = (const int*)d_in[1];
    const float* w1    = (const float*)d_in[2];
    const float* gamma = (const float*)d_in[3];
    const float* beta  = (const float*)d_in[4];
    const float* w2    = (const float*)d_in[5];
    const float* b2    = (const float*)d_in[6];
    float* out = (float*)d_out;

    char* ws = (char*)d_ws;
    int*    qi     = (int*)(ws + OFF_QI);
    int*    qj     = (int*)(ws + OFF_QJ);
    int*    qidx   = (int*)(ws + OFF_QIDX);
    int*    apix   = (int*)(ws + OFF_APIX);
    double* part   = (double*)(ws + OFF_PART);
    float*  scores = (float*)(ws + OFF_SC);
    float*  hm     = (float*)(ws + OFF_HM);
    unsigned short* AhU = (unsigned short*)(ws + OFF_AH);
    unsigned short* AlU = (unsigned short*)(ws + OFF_AL);
    unsigned short* BhU = (unsigned short*)(ws + OFF_BH);
    unsigned short* BlU = (unsigned short*)(ws + OFF_BL);
    float*  Yt     = (float*)(ws + OFF_YT);
    float*  X      = (float*)(ws + OFF_X);   // aliases Yt head

    // allow 144 KB dynamic LDS for k_gemm (one-time host-side attribute)
    static bool gemm_attr_set = false;
    if (!gemm_attr_set) {
        hipFuncSetAttribute((const void*)k_gemm,
                            hipFuncAttributeMaxDynamicSharedMemorySize, 2 * BUFSZ);
        gemm_attr_set = true;
    }

    k_fill<<<64, 256, 0, stream>>>(qi, qj, qidx, apix, part);
    k_buildX<<<768, 128, 0, stream>>>(fea, qi, qj, X);
    k_prepA<<<dim3(12, 12), 256, 0, stream>>>(w1, AhU, AlU);
    k_trans<<<dim3(40, 12), 256, 0, stream>>>(X, NPAD, BhU, BlU);
    k_gemm<<<dim3(216), 512, 2 * BUFSZ, stream>>>(AhU, AlU, BhU, BlU, Yt);
    k_gather<<<512, 256, 0, stream>>>(Yt, qidx, apix, hm, part);
    k_score<<<637, 256, 0, stream>>>(hm, part, gamma, beta, w2, b2, scores);
    k_nms<<<1, 1024, 0, stream>>>(scores, qi, qj, dur, out);
}

// Round 7
// 279.494 us; speedup vs baseline: 1.2777x; 1.2777x over previous
//
#include <hip/hip_runtime.h>
#include <math.h>

// ---------------- problem constants ----------------
#define NPIX 128
#define MASKM 2548
#define NPAD 2560          // padded q count (20*128)
#define MG   6912          // GEMM M = 9 taps * 768
#define KD   768

typedef __attribute__((ext_vector_type(8))) short bf16x8;
typedef __attribute__((ext_vector_type(4))) float f32x4;
typedef __attribute__((ext_vector_type(16))) float f32x16;
typedef __attribute__((ext_vector_type(8))) unsigned short ushort8;

// ---------------- workspace layout ----------------
static constexpr size_t OFF_QI   = 0;
static constexpr size_t OFF_QJ   = OFF_QI + NPAD * 4;
static constexpr size_t OFF_QIDX = OFF_QJ + NPAD * 4;
static constexpr size_t OFF_APIX = OFF_QIDX + 16384 * 4;
static constexpr size_t OFF_START= OFF_APIX + 16384 * 4;
static constexpr size_t OFF_PART = OFF_START + 128 * 4;
static constexpr size_t OFF_STAT = OFF_PART + 512 * 8 * 8;
static constexpr size_t OFF_SC   = OFF_STAT + 256;
static constexpr size_t OFF_HM   = OFF_SC + NPAD * 4;
static constexpr size_t OFF_AH   = OFF_HM + (size_t)MASKM * KD * 4;
static constexpr size_t OFF_AL   = OFF_AH + (size_t)MG * KD * 2;
static constexpr size_t OFF_BH   = OFF_AL + (size_t)MG * KD * 2;
static constexpr size_t OFF_BL   = OFF_BH + (size_t)NPAD * KD * 2;
static constexpr size_t OFF_YT   = OFF_BL + (size_t)NPAD * KD * 2;
// X (7.9MB fp32) aliases the head of Yt (70.8MB): dead before k_gemm writes Yt.
static constexpr size_t OFF_X    = OFF_YT;

// ---------------- bf16 hi/lo split helpers ----------------
__device__ __forceinline__ unsigned short f2bf(float f) {
    unsigned u = __float_as_uint(f);
    u = u + 0x7FFFu + ((u >> 16) & 1u);       // RNE
    return (unsigned short)(u >> 16);
}
__device__ __forceinline__ float bf2f(unsigned short h) {
    return __uint_as_float(((unsigned)h) << 16);
}

// ---------------- mask structure (closed form) ----------------
__device__ __forceinline__ bool mask_allowed(int i, int d) {
    if (d == 0) return true;
    if (d <= 15) return true;
    if (d <= 31) return (d >= 17) && ((d & 1) == 1) && ((i & 1) == 0);
    if (d <= 63) return (d >= 35) && ((d & 3) == 3) && ((i & 3) == 0);
    return (d >= 71) && ((d & 7) == 7) && ((i & 7) == 0);
}
__device__ __forceinline__ bool masked_ij(int i, int j) {
    return (j >= i) && (j < NPIX) && (i >= 0) && mask_allowed(i, j - i);
}

// 64 blocks x 256: one thread per pixel -> qidx, apix, qi/qj.
// Row-start offsets recomputed per block in LDS (absorbs old k_rowstart).
// Block 0 also zeroes the 8 GN accumulator doubles (read by k_score).
__global__ void k_fill(int* __restrict__ qi, int* __restrict__ qj,
                       int* __restrict__ qidx, int* __restrict__ apix,
                       double* __restrict__ part) {
    __shared__ int cnt[NPIX];
    __shared__ int startv[NPIX];
    int tid = threadIdx.x;
    if (tid < NPIX) {
        int c = 0;
        for (int d = 0; tid + d < NPIX; ++d) if (mask_allowed(tid, d)) ++c;
        cnt[tid] = c;
    }
    __syncthreads();
    if (tid == 0) {
        int s = 0;
        for (int r = 0; r < NPIX; ++r) { startv[r] = s; s += cnt[r]; }
    }
    __syncthreads();
    int p = blockIdx.x * 256 + tid;
    int i = p >> 7, j = p & 127;
    int q = -1;
    if (masked_ij(i, j)) {
        int d = j - i, r = 0;
        for (int dd = 0; dd < d; ++dd) r += mask_allowed(i, dd) ? 1 : 0;
        q = startv[i] + r;
        qi[q] = i; qj[q] = j;
    }
    qidx[p] = q;
    int act = 0;
    #pragma unroll
    for (int dy = -1; dy <= 1; ++dy)
        #pragma unroll
        for (int dx = -1; dx <= 1; ++dx)
            if (masked_ij(i + dy, j + dx)) act = 1;
    apix[p] = act;
    if (blockIdx.x == 0 && tid < 8) part[tid] = 0.0;
}

// ---------------- X[c][q] = max(fea[c, i..j]) via sparse table ----------------
__global__ void k_buildX(const float* __restrict__ fea, const int* __restrict__ qi,
                         const int* __restrict__ qj, float* __restrict__ X) {
    __shared__ float tab[8][NPIX];
    int c = blockIdx.x, t = threadIdx.x;    // 128 threads
    tab[0][t] = fea[c * NPIX + t];
    __syncthreads();
    #pragma unroll
    for (int l = 1; l < 8; ++l) {
        int half = 1 << (l - 1), full = 1 << l;
        if (t + full <= NPIX) tab[l][t] = fmaxf(tab[l - 1][t], tab[l - 1][t + half]);
        __syncthreads();
    }
    #pragma unroll
    for (int it = 0; it < 20; ++it) {
        int q = it * 128 + t;
        float v = 0.f;
        if (q < MASKM) {
            int i = qi[q], j = qj[q];
            int len = j - i + 1;
            int l = 31 - __clz(len);
            v = fmaxf(tab[l][i], tab[l][j + 1 - (1 << l)]);
        }
        X[c * NPAD + q] = v;
    }
}

// ---------------- fused reorder+split: w1[co][ci*9+tap] -> Ah/Al[(tap*768+co)][ci] ----------------
#define PASTR 148   // padded float stride (148*4 B: 16B-aligned, non-pow2 banks)
__global__ __launch_bounds__(256) void k_prepA(const float* __restrict__ w1,
                                               unsigned short* __restrict__ Ah,
                                               unsigned short* __restrict__ Al) {
    __shared__ float tile[64 * PASTR];   // [co 64][ci16*9tap = 144 used]
    int co0 = blockIdx.x * 64, ci0 = blockIdx.y * 64;
    int tid = threadIdx.x;
    for (int s = 0; s < 4; ++s) {
        int cib = ci0 + s * 16;
        __syncthreads();
        for (int idx = tid; idx < 2304; idx += 256) {
            int row = idx / 36, c4 = idx % 36;
            float4 v = *(const float4*)(w1 + (size_t)(co0 + row) * MG + cib * 9 + c4 * 4);
            *(float4*)&tile[row * PASTR + c4 * 4] = v;
        }
        __syncthreads();
        for (int idx = tid; idx < 1152; idx += 256) {
            int tap = idx / 128;
            int rem = idx - tap * 128;
            int co = rem >> 1, half = rem & 1;
            ushort8 vh, vl;
            #pragma unroll
            for (int c = 0; c < 8; ++c) {
                float v = tile[co * PASTR + (half * 8 + c) * 9 + tap];
                unsigned short hi = f2bf(v);
                vh[c] = hi;
                vl[c] = f2bf(v - bf2f(hi));
            }
            size_t ob = (size_t)(tap * 768 + co0 + co) * KD + cib + half * 8;
            *(ushort8*)(Ah + ob) = vh;
            *(ushort8*)(Al + ob) = vl;
        }
    }
}

// ---------------- transpose + bf16 hi/lo split: src[768][C] -> dst[C][768] ----------------
__global__ void k_trans(const float* __restrict__ src, int C,
                        unsigned short* __restrict__ dh, unsigned short* __restrict__ dl) {
    __shared__ float tile[64][65];
    int c0 = blockIdx.x * 64, k0 = blockIdx.y * 64;
    int t = threadIdx.x;
    int r = t >> 2, cq = (t & 3) << 4;
    const float* s = src + (size_t)(k0 + r) * C + c0 + cq;
    #pragma unroll
    for (int u = 0; u < 16; u += 4) {
        float4 v = *(const float4*)(s + u);
        tile[r][cq + u]     = v.x;
        tile[r][cq + u + 1] = v.y;
        tile[r][cq + u + 2] = v.z;
        tile[r][cq + u + 3] = v.w;
    }
    __syncthreads();
    size_t ob = (size_t)(c0 + r) * KD + k0 + cq;
    #pragma unroll
    for (int u = 0; u < 16; ++u) {
        float v = tile[cq + u][r];
        unsigned short hi = f2bf(v);
        float lo = v - bf2f(hi);
        dh[ob + u] = hi;
        dl[ob + u] = f2bf(lo);
    }
}

// ---------------- bf16x3 MFMA GEMM: Yt[n][m] = sum_k A[m][k] * B[n][k] ----------------
// 32x32x16 MFMA, BM=256 BN=320 BK=32, grid = 216 = 8 XCD x 27 (one round).
// Chunk-major LDS slots (R4: 0 bank conflicts). Lessons applied:
//   R4: sched_barrier(0) fences serialize LDS vs MFMA -> 9600 cyc/tile (m141 trap).
//   R5/R6: 22-frag-deep order spills at the compiler's hard 128 arch-VGPR choice
//          (launch_bounds hint has NO effect: R6 A/B) -> scratch traffic, 170us.
// R7: bounded-liveness rotation, NO fences: B-frags for phase n+1 loaded between
// MFMA clusters of phase n (two rotating register pairs bx/by). Max live = 4 A +
// 4 B frags = 32 VGPR + addressing -> fits 128, and the pressure-aware scheduler
// (m97: emits counted lgkmcnt on its own) is free to overlap reads with MFMAs.
#define BUFSZ   73728      // Ah(16K) | Al(16K) | Bh(20K) | Bl(20K)
#define SB_BH   32768

__global__ __launch_bounds__(512, 1) void k_gemm(const unsigned short* __restrict__ Ah,
                                                 const unsigned short* __restrict__ Al,
                                                 const unsigned short* __restrict__ Bh,
                                                 const unsigned short* __restrict__ Bl,
                                                 float* __restrict__ Yt) {
    extern __shared__ char sm[];               // 2 * BUFSZ = 144 KB dynamic LDS
    int tid = threadIdx.x;
    int wave = tid >> 6, lane = tid & 63;

    int bid = (int)blockIdx.x;
    int xcd = bid & 7, loc = bid >> 3;         // 8 XCDs x 27 M-tiles
    int m0 = loc * 256, n0 = xcd * 320;

    int wm = (wave & 3) << 6, wn = (wave >> 2) * 160;  // 4M x 2N waves, 64x160/wave
    int r32 = lane & 31, hi2 = lane >> 5;
    // common fragment-read base: slot(row>>4)*1024 + hi2*256 + (row&15)*16
    int rb  = (r32 >> 4) * 1024 + hi2 * 256 + (r32 & 15) * 16;
    int awb = (wm >> 4) * 1024 + rb;
    int bwb = (wn >> 4) * 1024 + rb;

    // 9 stage slots per wave: gid = wave*9+s over 72 total.
    // gid 0-15: Ah 16-row slots; 16-31: Al; 32-51: Bh; 52-71: Bl.
    // chunk-major staging: lane stages row (lane&15), k-chunk (lane>>4).
    int lrow = lane & 15, lchk = lane >> 4;
    const unsigned short* sp[9];
    int so[9];
    #pragma unroll
    for (int s = 0; s < 9; ++s) {
        int gid = wave * 9 + s;
        const unsigned short* base;
        int row0, ldso;
        if (gid < 16)      { base = Ah; row0 = m0 + gid * 16;        ldso = gid * 1024; }
        else if (gid < 32) { base = Al; row0 = m0 + (gid - 16) * 16; ldso = 16384 + (gid - 16) * 1024; }
        else if (gid < 52) { base = Bh; row0 = n0 + (gid - 32) * 16; ldso = SB_BH + (gid - 32) * 1024; }
        else               { base = Bl; row0 = n0 + (gid - 52) * 16; ldso = SB_BH + 20480 + (gid - 52) * 1024; }
        sp[s] = base + (size_t)(row0 + lrow) * KD + lchk * 8;
        so[s] = ldso;
    }

    f32x16 acc[2][5] = {};                     // 2 m-frags x 5 n-frags of 32x32

    char* CB = sm;                             // compute buffer
    char* NB = sm + BUFSZ;                     // staging buffer (next tile)

    #define STAGE(DST, s, koff) __builtin_amdgcn_global_load_lds( \
        (const __attribute__((address_space(1))) unsigned int*)(sp[s] + (koff)), \
        (__attribute__((address_space(3))) unsigned int*)((DST) + so[s]), 16, 0, 0)
    #define ARD(hl, mf, ks) (*(const bf16x8*)(CB + (hl) * 16384 + awb + (mf) * 2048 + (ks) * 512))
    #define BRD(hl, nf, ks) (*(const bf16x8*)(CB + SB_BH + (hl) * 20480 + bwb + (nf) * 2048 + (ks) * 512))
    #define TRIP(mf, nf, xh, xl, yh, yl) \
        acc[mf][nf] = __builtin_amdgcn_mfma_f32_32x32x16_bf16(xh, yh, acc[mf][nf], 0, 0, 0); \
        acc[mf][nf] = __builtin_amdgcn_mfma_f32_32x32x16_bf16(xh, yl, acc[mf][nf], 0, 0, 0); \
        acc[mf][nf] = __builtin_amdgcn_mfma_f32_32x32x16_bf16(xl, yh, acc[mf][nf], 0, 0, 0);

    // prologue: stage tile 0 into CB; __syncthreads drains vmcnt.
    #pragma unroll
    for (int s = 0; s < 9; ++s) STAGE(CB, s, 0);
    __syncthreads();

    for (int t = 0; t < 24; ++t) {             // K = 768 = 24 tiles of 32
        int kn = (t + 1) * 32;
        // next-tile staging first (VMEM pipe; drains at tile-end barrier)
        if (t < 23) {
            #pragma unroll
            for (int s = 0; s < 9; ++s) STAGE(NB, s, kn);
        }
        #pragma unroll
        for (int ks = 0; ks < 2; ++ks) {
            // phase reads rotate through two register pairs (bx, by):
            // reads for phase n+1 sit between the MFMA clusters of phase n.
            bf16x8 a0h = ARD(0, 0, ks), a0l = ARD(1, 0, ks);
            bf16x8 a1h = ARD(0, 1, ks), a1l = ARD(1, 1, ks);
            bf16x8 bxh = BRD(0, 0, ks), bxl = BRD(1, 0, ks);
            bf16x8 byh = BRD(0, 1, ks), byl = BRD(1, 1, ks);
            __builtin_amdgcn_s_setprio(1);
            TRIP(0, 0, a0h, a0l, bxh, bxl)
            TRIP(1, 0, a1h, a1l, bxh, bxl)
            __builtin_amdgcn_s_setprio(0);
            bxh = BRD(0, 2, ks); bxl = BRD(1, 2, ks);
            __builtin_amdgcn_s_setprio(1);
            TRIP(0, 1, a0h, a0l, byh, byl)
            TRIP(1, 1, a1h, a1l, byh, byl)
            __builtin_amdgcn_s_setprio(0);
            byh = BRD(0, 3, ks); byl = BRD(1, 3, ks);
            __builtin_amdgcn_s_setprio(1);
            TRIP(0, 2, a0h, a0l, bxh, bxl)
            TRIP(1, 2, a1h, a1l, bxh, bxl)
            __builtin_amdgcn_s_setprio(0);
            bxh = BRD(0, 4, ks); bxl = BRD(1, 4, ks);
            __builtin_amdgcn_s_setprio(1);
            TRIP(0, 3, a0h, a0l, byh, byl)
            TRIP(1, 3, a1h, a1l, byh, byl)
            TRIP(0, 4, a0h, a0l, bxh, bxl)
            TRIP(1, 4, a1h, a1l, bxh, bxl)
            __builtin_amdgcn_s_setprio(0);
        }
        // tile boundary: drains vmcnt (next-tile stages resident) and gates the
        // buffer swap (all waves done reading CB).
        __syncthreads();
        char* tmp = CB; CB = NB; NB = tmp;
    }

    // epilogue: C/D layout of 32x32: col(n)=lane&31, row(m)=(reg&3)+8*(reg>>2)+4*(lane>>5)
    #pragma unroll
    for (int mf = 0; mf < 2; ++mf)
        #pragma unroll
        for (int nf = 0; nf < 5; ++nf) {
            int n = n0 + wn + nf * 32 + r32;
            size_t rowb = (size_t)n * MG + m0 + wm + mf * 32 + 4 * hi2;
            #pragma unroll
            for (int g = 0; g < 4; ++g) {
                f32x4 v = { acc[mf][nf][g * 4 + 0], acc[mf][nf][g * 4 + 1],
                            acc[mf][nf][g * 4 + 2], acc[mf][nf][g * 4 + 3] };
                *(f32x4*)(Yt + rowb + 8 * g) = v;
            }
        }
    #undef STAGE
    #undef ARD
    #undef BRD
    #undef TRIP
}

// ---------------- gather taps -> hm (masked rows) + GN partial sums (active pixels only) ----------------
__global__ __launch_bounds__(256) void k_gather(const float* __restrict__ Yt,
                                                const int* __restrict__ qidx,
                                                const int* __restrict__ apix,
                                                float* __restrict__ hm,
                                                double* __restrict__ part) {
    __shared__ double red1[256 * 4], red2[256 * 4];
    int tid = threadIdx.x;
    int wave = tid >> 6, lane = tid & 63;
    double a1[3] = {0, 0, 0}, a2[3] = {0, 0, 0};
    int gs[3];
    #pragma unroll
    for (int s = 0; s < 3; ++s) gs[s] = (64 * s + lane) / 48;

    for (int it = 0; it < 8; ++it) {
        int p = blockIdx.x * 32 + wave * 8 + it;   // wave-uniform pixel
        if (!apix[p]) continue;
        int y = p >> 7, x = p & 127;
        float4 hv[3] = {};
        #pragma unroll
        for (int tap = 0; tap < 9; ++tap) {
            int i = y + tap / 3 - 1, j = x + tap % 3 - 1;
            if ((unsigned)i < 128u && (unsigned)j < 128u) {
                int q = qidx[i * NPIX + j];
                if (q >= 0) {
                    const float* yr = Yt + (size_t)q * MG + tap * 768 + lane * 4;
                    #pragma unroll
                    for (int s = 0; s < 3; ++s) {
                        float4 v = *(const float4*)(yr + s * 256);
                        hv[s].x += v.x; hv[s].y += v.y; hv[s].z += v.z; hv[s].w += v.w;
                    }
                }
            }
        }
        int qp = qidx[p];
        if (qp >= 0) {
            #pragma unroll
            for (int s = 0; s < 3; ++s)
                *(float4*)(hm + (size_t)qp * KD + s * 256 + lane * 4) = hv[s];
        }
        #pragma unroll
        for (int s = 0; s < 3; ++s) {
            a1[s] += (double)hv[s].x + (double)hv[s].y + (double)hv[s].z + (double)hv[s].w;
            a2[s] += (double)hv[s].x * hv[s].x + (double)hv[s].y * hv[s].y +
                     (double)hv[s].z * hv[s].z + (double)hv[s].w * hv[s].w;
        }
    }
    #pragma unroll
    for (int g = 0; g < 4; ++g) { red1[tid * 4 + g] = 0.0; red2[tid * 4 + g] = 0.0; }
    #pragma unroll
    for (int s = 0; s < 3; ++s) { red1[tid * 4 + gs[s]] = a1[s]; red2[tid * 4 + gs[s]] = a2[s]; }
    __syncthreads();
    if (tid < 8) {
        int g = tid & 3;
        double s = 0.0;
        if (tid < 4) { for (int i = 0; i < 256; ++i) s += red1[i * 4 + g]; }
        else         { for (int i = 0; i < 256; ++i) s += red2[i * 4 + g]; }
        atomicAdd(&part[tid], s);
    }
}

// ---------------- fused GN + ReLU + 1x1 conv + sigmoid at mask positions ----------------
__global__ void k_score(const float* __restrict__ hm, const double* __restrict__ part,
                        const float* __restrict__ gamma, const float* __restrict__ beta,
                        const float* __restrict__ w2, const float* __restrict__ b2,
                        float* __restrict__ scores) {
    int q = blockIdx.x * 4 + (threadIdx.x >> 6);
    int lane = threadIdx.x & 63;
    if (q >= MASKM) return;
    float mu[4], rs[4];
    const double cnt = 192.0 * 16384.0;
    #pragma unroll
    for (int g = 0; g < 4; ++g) {
        double m = part[g] / cnt;
        double v = part[4 + g] / cnt - m * m;
        mu[g] = (float)m;
        rs[g] = (float)(1.0 / sqrt(v + 1e-5));
    }
    const float* hp = hm + (size_t)q * KD;
    float s = 0.f;
    for (int c = lane; c < KD; c += 64) {
        int g = c / 192;
        float v = (hp[c] - mu[g]) * rs[g] * gamma[c] + beta[c];
        s += fmaxf(v, 0.f) * w2[c];
    }
    for (int o = 32; o; o >>= 1) s += __shfl_down(s, o, 64);
    if (lane == 0) scores[q] = 1.f / (1.f + expf(-(s + b2[0])));
}

// ---------------- greedy NMS via 5-round iterative argmax (== stable sorted greedy) ----------------
__device__ __forceinline__ unsigned long long shfl_down_u64(unsigned long long v, int o) {
    unsigned lo = (unsigned)v, hi = (unsigned)(v >> 32);
    lo = __shfl_down(lo, o, 64);
    hi = __shfl_down(hi, o, 64);
    return ((unsigned long long)hi << 32) | lo;
}

__global__ void k_nms(const float* __restrict__ scores, const int* __restrict__ qi,
                      const int* __restrict__ qj, const int* __restrict__ durp,
                      float* __restrict__ out) {
    __shared__ unsigned long long key[MASKM];
    __shared__ float ss[MASKM], ee[MASKM];
    __shared__ unsigned char st[MASKM];     // 0 free, 1 suppressed, 2 kept, 3 picked-fallback
    __shared__ unsigned long long wm0[16], wm1[16];
    __shared__ int sh_keeper, keepq[5];
    __shared__ float sh_s0, sh_e0;
    int t = threadIdx.x;                    // 1024
    float delta = (float)(*durp) / 128.f;
    for (int i = t; i < MASKM; i += 1024) {
        unsigned sb = __float_as_uint(scores[i]);            // scores > 0: bits monotonic
        key[i] = ((unsigned long long)sb << 32) | (unsigned)(4095 - i);  // tie: lower q wins
        ss[i] = qi[i] * delta;
        ee[i] = (qj[i] + 1) * delta;
        st[i] = 0;
    }
    __syncthreads();
    for (int round = 0; round < 5; ++round) {
        unsigned long long b0 = 0, b1 = 0;
        for (int i = t; i < MASKM; i += 1024) {
            unsigned char s = st[i];
            unsigned long long k = key[i];
            if (s == 0) { if (k > b0) b0 = k; }
            else if (s == 1) { if (k > b1) b1 = k; }
        }
        for (int o = 32; o; o >>= 1) {
            unsigned long long u0 = shfl_down_u64(b0, o), u1 = shfl_down_u64(b1, o);
            if (u0 > b0) b0 = u0;
            if (u1 > b1) b1 = u1;
        }
        if ((t & 63) == 0) { wm0[t >> 6] = b0; wm1[t >> 6] = b1; }
        __syncthreads();
        if (t == 0) {
            unsigned long long B0 = 0, B1 = 0;
            for (int w = 0; w < 16; ++w) {
                if (wm0[w] > B0) B0 = wm0[w];
                if (wm1[w] > B1) B1 = wm1[w];
            }
            int keeper = (B0 != 0);
            unsigned long long B = keeper ? B0 : B1;
            int q = 4095 - (int)(B & 0xFFFFFFFFull);
            st[q] = keeper ? 2 : 3;
            sh_keeper = keeper;
            sh_s0 = ss[q]; sh_e0 = ee[q];
            keepq[round] = q;
        }
        __syncthreads();
        if (sh_keeper) {
            float s0 = sh_s0, e0 = sh_e0;
            for (int i = t; i < MASKM; i += 1024) {
                if (st[i] == 0) {
                    float inter = fminf(ee[i], e0) - fmaxf(ss[i], s0);
                    if (inter > 0.f) {
                        float uni = fmaxf(ee[i], e0) - fminf(ss[i], s0);
                        if (inter / uni > 0.5f) st[i] = 1;
                    }
                }
            }
        }
        __syncthreads();
    }
    if (t < 5) { out[t * 2] = ss[keepq[t]]; out[t * 2 + 1] = ee[keepq[t]]; }
}

// ---------------- launch ----------------
extern "C" void kernel_launch(void* const* d_in, const int* in_sizes, int n_in,
                              void* d_out, int out_size, void* d_ws, size_t ws_size,
                              hipStream_t stream) {
    const float* fea   = (const float*)d_in[0];
    const int*   dur   = (const int*)d_in[1];
    const float* w1    = (const float*)d_in[2];
    const float* gamma = (const float*)d_in[3];
    const float* beta  = (const float*)d_in[4];
    const float* w2    = (const float*)d_in[5];
    const float* b2    = (const float*)d_in[6];
    float* out = (float*)d_out;

    char* ws = (char*)d_ws;
    int*    qi     = (int*)(ws + OFF_QI);
    int*    qj     = (int*)(ws + OFF_QJ);
    int*    qidx   = (int*)(ws + OFF_QIDX);
    int*    apix   = (int*)(ws + OFF_APIX);
    double* part   = (double*)(ws + OFF_PART);
    float*  scores = (float*)(ws + OFF_SC);
    float*  hm     = (float*)(ws + OFF_HM);
    unsigned short* AhU = (unsigned short*)(ws + OFF_AH);
    unsigned short* AlU = (unsigned short*)(ws + OFF_AL);
    unsigned short* BhU = (unsigned short*)(ws + OFF_BH);
    unsigned short* BlU = (unsigned short*)(ws + OFF_BL);
    float*  Yt     = (float*)(ws + OFF_YT);
    float*  X      = (float*)(ws + OFF_X);   // aliases Yt head

    // allow 144 KB dynamic LDS for k_gemm (one-time host-side attribute)
    static bool gemm_attr_set = false;
    if (!gemm_attr_set) {
        hipFuncSetAttribute((const void*)k_gemm,
                            hipFuncAttributeMaxDynamicSharedMemorySize, 2 * BUFSZ);
        gemm_attr_set = true;
    }

    k_fill<<<64, 256, 0, stream>>>(qi, qj, qidx, apix, part);
    k_buildX<<<768, 128, 0, stream>>>(fea, qi, qj, X);
    k_prepA<<<dim3(12, 12), 256, 0, stream>>>(w1, AhU, AlU);
    k_trans<<<dim3(40, 12), 256, 0, stream>>>(X, NPAD, BhU, BlU);
    k_gemm<<<dim3(216), 512, 2 * BUFSZ, stream>>>(AhU, AlU, BhU, BlU, Yt);
    k_gather<<<512, 256, 0, stream>>>(Yt, qidx, apix, hm, part);
    k_score<<<637, 256, 0, stream>>>(hm, part, gamma, beta, w2, b2, scores);
    k_nms<<<1, 1024, 0, stream>>>(scores, qi, qj, dur, out);
}